// Round 1
// baseline (167.656 us; speedup 1.0000x reference)
//
#include <hip/hip_runtime.h>

#define BB   8
#define SS   4096
#define DD   64
#define NBB  32

typedef float f32x4 __attribute__((ext_vector_type(4)));
typedef short s16x8 __attribute__((ext_vector_type(8)));

#if defined(__has_builtin)
#if __has_builtin(__builtin_amdgcn_exp2f)
#define EXP2(x) __builtin_amdgcn_exp2f(x)
#else
#define EXP2(x) exp2f(x)
#endif
#else
#define EXP2(x) exp2f(x)
#endif

#define MFMA16(a, b, c) __builtin_amdgcn_mfma_f32_16x16x32_bf16((a), (b), (c), 0, 0, 0)

__device__ __forceinline__ unsigned short f2bf(float x) {
  // round-to-nearest-even fp32 -> bf16 (inputs are finite; no NaN handling needed)
  unsigned u = __builtin_bit_cast(unsigned, x);
  u += 0x7fffu + ((u >> 16) & 1u);
  return (unsigned short)(u >> 16);
}

// One workgroup per (batch, q-block). 8 waves: wq = wid>>1 (q rows 32*wq..),
// wk = wid&1 (kv half 64*wk..). Separate online-softmax state per wave,
// merged across the two kv halves at the end.
__global__ __launch_bounds__(512) void bsattn_kernel(
    const float* __restrict__ qp, const float* __restrict__ kp,
    const float* __restrict__ vp, const int* __restrict__ layout,
    float* __restrict__ out) {
  __shared__ alignas(16) char smem[65536];
  char* Klds = smem;             // 128 rows x 128 B (bf16 K, row-major, swizzled)
  char* VTlds = smem + 16384;    // 64 rows x 256 B (bf16 V^T, swizzled)
  char* Pall = smem + 32768;     // 8 waves x 4096 B (bf16 P, 32x64 per wave)

  const int tid = threadIdx.x;
  const int lane = tid & 63;
  const int wid = tid >> 6;
  const int wq = wid >> 1;
  const int wk = wid & 1;
  const int l16 = lane & 15;
  const int lg = lane >> 4;  // 0..3

  char* Plds = Pall + wid * 4096;

  const int bidx = blockIdx.x;
  const int b = bidx & 7;        // XCD-friendly: one batch per XCD (round-robin dispatch)
  const int qb = bidx >> 3;

  // ---- Q fragments in registers, scaled by log2(e)/sqrt(D) ----
  const float qscale = 0.18033688011112042f;  // 1.4426950408889634 / 8
  s16x8 qf[2][2];
  {
    const float* qb_ptr = qp + ((size_t)b * SS + (size_t)qb * 128 + wq * 32) * DD;
#pragma unroll
    for (int qc = 0; qc < 2; ++qc) {
      const float* qrow = qb_ptr + (qc * 16 + l16) * DD;
#pragma unroll
      for (int kc = 0; kc < 2; ++kc) {
        const float* p0 = qrow + kc * 32 + lg * 8;
        float4 x = *(const float4*)(p0);
        float4 y = *(const float4*)(p0 + 4);
        s16x8 f;
        f[0] = (short)f2bf(x.x * qscale); f[1] = (short)f2bf(x.y * qscale);
        f[2] = (short)f2bf(x.z * qscale); f[3] = (short)f2bf(x.w * qscale);
        f[4] = (short)f2bf(y.x * qscale); f[5] = (short)f2bf(y.y * qscale);
        f[6] = (short)f2bf(y.z * qscale); f[7] = (short)f2bf(y.w * qscale);
        qf[qc][kc] = f;
      }
    }
  }

  f32x4 o_acc[2][4];
  float m2[2][4], ls[2][4];
#pragma unroll
  for (int qc = 0; qc < 2; ++qc) {
#pragma unroll
    for (int j = 0; j < 4; ++j) {
      o_acc[qc][j] = (f32x4)(0.0f);
      m2[qc][j] = -INFINITY;
      ls[qc][j] = 0.0f;
    }
  }

  const float* kbase0 = kp + (size_t)b * SS * DD;
  const float* vbase0 = vp + (size_t)b * SS * DD;
  const int drow = tid & 15;        // d-group for staging (4 floats)
  const int rr0 = tid >> 4;         // 0..31: row within staging pass

  for (int kb = 0; kb < NBB; ++kb) {
    if (layout[qb * NBB + kb] == 0) continue;
    __syncthreads();  // previous block's LDS reads complete before overwrite
    // ---- stage K (row-major bf16, swizzled) and V^T (transposed bf16, swizzled) ----
    {
      const float* kbp = kbase0 + (size_t)kb * 128 * DD;
#pragma unroll
      for (int p = 0; p < 4; ++p) {
        int row = rr0 + p * 32;
        float4 kx = *(const float4*)(kbp + row * DD + drow * 4);
        ushort4 kbf;
        kbf.x = f2bf(kx.x); kbf.y = f2bf(kx.y); kbf.z = f2bf(kx.z); kbf.w = f2bf(kx.w);
        int col = (drow * 8) ^ ((row & 7) << 4);
        *(ushort4*)(Klds + row * 128 + col) = kbf;
      }
      const float* vbp = vbase0 + (size_t)kb * 128 * DD;
#pragma unroll
      for (int p = 0; p < 4; ++p) {
        int kvr = rr0 + p * 32;
        float4 vx = *(const float4*)(vbp + kvr * DD + drow * 4);
        int d0 = drow * 4;
        *(unsigned short*)(VTlds + (d0 + 0) * 256 + ((kvr * 2) ^ (((d0 + 0) & 7) << 4))) = f2bf(vx.x);
        *(unsigned short*)(VTlds + (d0 + 1) * 256 + ((kvr * 2) ^ (((d0 + 1) & 7) << 4))) = f2bf(vx.y);
        *(unsigned short*)(VTlds + (d0 + 2) * 256 + ((kvr * 2) ^ (((d0 + 2) & 7) << 4))) = f2bf(vx.z);
        *(unsigned short*)(VTlds + (d0 + 3) * 256 + ((kvr * 2) ^ (((d0 + 3) & 7) << 4))) = f2bf(vx.w);
      }
    }
    __syncthreads();

    // ---- QK^T: S tile 32q x 64kv per wave ----
    f32x4 sc[2][4];
#pragma unroll
    for (int qc = 0; qc < 2; ++qc)
#pragma unroll
      for (int kvc = 0; kvc < 4; ++kvc) sc[qc][kvc] = (f32x4)(0.0f);

#pragma unroll
    for (int kvc = 0; kvc < 4; ++kvc) {
      int kvrow = wk * 64 + kvc * 16 + l16;
      const char* kr = Klds + kvrow * 128;
      int sw = (kvrow & 7) << 4;
#pragma unroll
      for (int kc = 0; kc < 2; ++kc) {
        s16x8 bk = *(const s16x8*)(kr + ((kc * 64 + lg * 16) ^ sw));
        sc[0][kvc] = MFMA16(qf[0][kc], bk, sc[0][kvc]);
        sc[1][kvc] = MFMA16(qf[1][kc], bk, sc[1][kvc]);
      }
    }

    // ---- online softmax (scores already in log2 units) ----
    float alpha[2][4];
#pragma unroll
    for (int qc = 0; qc < 2; ++qc) {
#pragma unroll
      for (int r = 0; r < 4; ++r) {
        float mx = fmaxf(fmaxf(sc[qc][0][r], sc[qc][1][r]),
                         fmaxf(sc[qc][2][r], sc[qc][3][r]));
        mx = fmaxf(mx, __shfl_xor(mx, 1));
        mx = fmaxf(mx, __shfl_xor(mx, 2));
        mx = fmaxf(mx, __shfl_xor(mx, 4));
        mx = fmaxf(mx, __shfl_xor(mx, 8));
        float mn = fmaxf(m2[qc][r], mx);
        float al = EXP2(m2[qc][r] - mn);
        m2[qc][r] = mn;
        alpha[qc][r] = al;
        float s0 = EXP2(sc[qc][0][r] - mn);
        float s1 = EXP2(sc[qc][1][r] - mn);
        float s2 = EXP2(sc[qc][2][r] - mn);
        float s3 = EXP2(sc[qc][3][r] - mn);
        sc[qc][0][r] = s0; sc[qc][1][r] = s1; sc[qc][2][r] = s2; sc[qc][3][r] = s3;
        float sm = (s0 + s1) + (s2 + s3);
        sm += __shfl_xor(sm, 1);
        sm += __shfl_xor(sm, 2);
        sm += __shfl_xor(sm, 4);
        sm += __shfl_xor(sm, 8);
        ls[qc][r] = ls[qc][r] * al + sm;
      }
    }

    // rescale O accumulators
#pragma unroll
    for (int qc = 0; qc < 2; ++qc)
#pragma unroll
      for (int dch = 0; dch < 4; ++dch)
#pragma unroll
        for (int r = 0; r < 4; ++r) o_acc[qc][dch][r] *= alpha[qc][r];

    // ---- P -> LDS (bf16, per-wave buffer, swizzled) ----
#pragma unroll
    for (int qc = 0; qc < 2; ++qc) {
#pragma unroll
      for (int r = 0; r < 4; ++r) {
        int qrow = qc * 16 + lg * 4 + r;
        char* pr = Plds + qrow * 128;
        int sw = (qrow & 7) << 4;
#pragma unroll
        for (int kvc = 0; kvc < 4; ++kvc) {
          *(unsigned short*)(pr + (((kvc * 16 + l16) * 2) ^ sw)) = f2bf(sc[qc][kvc][r]);
        }
      }
    }

    // ---- PV: O += P * V ----
#pragma unroll
    for (int kc2 = 0; kc2 < 2; ++kc2) {
      s16x8 pa[2];
#pragma unroll
      for (int qc = 0; qc < 2; ++qc) {
        int qrow = qc * 16 + l16;
        pa[qc] = *(const s16x8*)(Plds + qrow * 128 + ((kc2 * 64 + lg * 16) ^ ((qrow & 7) << 4)));
      }
#pragma unroll
      for (int dch = 0; dch < 4; ++dch) {
        int d = dch * 16 + l16;
        s16x8 vb = *(const s16x8*)(VTlds + d * 256 +
                                   ((wk * 128 + kc2 * 64 + lg * 16) ^ ((d & 7) << 4)));
        o_acc[0][dch] = MFMA16(pa[0], vb, o_acc[0][dch]);
        o_acc[1][dch] = MFMA16(pa[1], vb, o_acc[1][dch]);
      }
    }
  }

  // ---- merge the two kv halves (wk=1 publishes, wk=0 merges + stores) ----
  __syncthreads();
  float* Ol = (float*)smem;            // [4 wq][32 q][64 d] fp32 (aliases K+VT: 32 KB)
  float* Ml = (float*)(smem + 32768);  // m: [4][32], l at +128 floats (aliases P)
  if (wk == 1) {
#pragma unroll
    for (int qc = 0; qc < 2; ++qc) {
#pragma unroll
      for (int r = 0; r < 4; ++r) {
        int qrow = qc * 16 + lg * 4 + r;
        float* orow = Ol + (wq * 32 + qrow) * 64;
#pragma unroll
        for (int dch = 0; dch < 4; ++dch) orow[dch * 16 + l16] = o_acc[qc][dch][r];
        if (l16 == 0) {
          Ml[wq * 32 + qrow] = m2[qc][r];
          Ml[128 + wq * 32 + qrow] = ls[qc][r];
        }
      }
    }
  }
  __syncthreads();
  if (wk == 0) {
    float* obase = out + ((size_t)b * SS + (size_t)qb * 128 + wq * 32) * DD;
#pragma unroll
    for (int qc = 0; qc < 2; ++qc) {
#pragma unroll
      for (int r = 0; r < 4; ++r) {
        int qrow = qc * 16 + lg * 4 + r;
        float m1 = Ml[wq * 32 + qrow];
        float l1 = Ml[128 + wq * 32 + qrow];
        float mm = fmaxf(m2[qc][r], m1);
        float a0 = EXP2(m2[qc][r] - mm);
        float a1 = EXP2(m1 - mm);
        float inv = 1.0f / (ls[qc][r] * a0 + l1 * a1);
        const float* orow = Ol + (wq * 32 + qrow) * 64;
        float* gout = obase + qrow * DD;
#pragma unroll
        for (int dch = 0; dch < 4; ++dch) {
          int d = dch * 16 + l16;
          gout[d] = (o_acc[qc][dch][r] * a0 + orow[d] * a1) * inv;
        }
      }
    }
  }
}

extern "C" void kernel_launch(void* const* d_in, const int* in_sizes, int n_in,
                              void* d_out, int out_size, void* d_ws, size_t ws_size,
                              hipStream_t stream) {
  (void)in_sizes; (void)n_in; (void)d_ws; (void)ws_size; (void)out_size;
  const float* q = (const float*)d_in[0];
  const float* k = (const float*)d_in[1];
  const float* v = (const float*)d_in[2];
  const int* layout = (const int*)d_in[3];
  float* out = (float*)d_out;
  bsattn_kernel<<<dim3(BB * NBB), dim3(512), 0, stream>>>(q, k, v, layout, out);
}

// Round 2
// 127.627 us; speedup vs baseline: 1.3136x; 1.3136x over previous
//
#include <hip/hip_runtime.h>

#define BB   8
#define SS   4096
#define DD   64
#define NBB  32

typedef float f32x4 __attribute__((ext_vector_type(4)));
typedef short s16x8 __attribute__((ext_vector_type(8)));

#if defined(__has_builtin)
#if __has_builtin(__builtin_amdgcn_exp2f)
#define EXP2(x) __builtin_amdgcn_exp2f(x)
#else
#define EXP2(x) exp2f(x)
#endif
#else
#define EXP2(x) exp2f(x)
#endif

#define MFMA16(a, b, c) __builtin_amdgcn_mfma_f32_16x16x32_bf16((a), (b), (c), 0, 0, 0)

__device__ __forceinline__ unsigned short f2bf(float x) {
  unsigned u = __builtin_bit_cast(unsigned, x);
  u += 0x7fffu + ((u >> 16) & 1u);
  return (unsigned short)(u >> 16);
}

__device__ __forceinline__ void gl_lds16(const void* g, void* l) {
  __builtin_amdgcn_global_load_lds(
      (const __attribute__((address_space(1))) unsigned int*)g,
      (__attribute__((address_space(3))) unsigned int*)l, 16, 0, 0);
}

// ---------------- prep: K -> bf16 swizzled LDS image; V -> bf16 V^T swizzled image ----
// Image layout == exact LDS bytes the main kernel wants, so global_load_lds is linear.
// K image (16KB/block):  byte[row*128 + ((2d) ^ ((row&7)<<4))] = bf16(K[row][d])
// V image (16KB/block):  byte[d*256 + ((2kv) ^ ((d&7)<<4))]   = bf16(V[kv][d])
__global__ __launch_bounds__(256) void bsattn_prep(
    const float* __restrict__ kp, const float* __restrict__ vp,
    char* __restrict__ kimg, char* __restrict__ vimg) {
  __shared__ float vt[128 * 68];  // fp32 V tile, padded (bank stride 68)
  const int tid = threadIdx.x;
  const int blk = blockIdx.x;  // b*NBB + kb
  const float* kbp = kp + (size_t)blk * 128 * DD;
  const float* vbp = vp + (size_t)blk * 128 * DD;
  char* kdst = kimg + ((size_t)blk << 14);
  char* vdst = vimg + ((size_t)blk << 14);
  const int drow = tid & 15, rr = tid >> 4;
#pragma unroll
  for (int p = 0; p < 8; ++p) {
    int row = p * 16 + rr;
    float4 kx = *(const float4*)(kbp + row * DD + drow * 4);
    ushort4 k4;
    k4.x = f2bf(kx.x); k4.y = f2bf(kx.y); k4.z = f2bf(kx.z); k4.w = f2bf(kx.w);
    *(ushort4*)(kdst + row * 128 + ((drow * 8) ^ ((row & 7) << 4))) = k4;
    float4 vx = *(const float4*)(vbp + row * DD + drow * 4);
    *(float4*)(&vt[row * 68 + drow * 4]) = vx;
  }
  __syncthreads();
  const int l5 = tid & 31, dhi = tid >> 5;
#pragma unroll
  for (int p = 0; p < 8; ++p) {
    int d = p * 8 + dhi;
    int kv0 = l5 * 4;
    ushort4 v4;
    v4.x = f2bf(vt[(kv0 + 0) * 68 + d]);
    v4.y = f2bf(vt[(kv0 + 1) * 68 + d]);
    v4.z = f2bf(vt[(kv0 + 2) * 68 + d]);
    v4.w = f2bf(vt[(kv0 + 3) * 68 + d]);
    *(ushort4*)(vdst + d * 256 + ((kv0 * 2) ^ ((d & 7) << 4))) = v4;
  }
}

// ---------------- main: WG = (b, qb, half): 64 q rows, 4 waves ----------------------
// wave = (wq = wid>>1: 32-q sub-tile) x (wk = wid&1: 64-kv half). Swapped MFMA:
// QK^T: mfma(A=Kfrag, B=Qfrag) -> S^T, lane owns q = lane&15. Softmax: 2 shfl/reduce.
// PV:   mfma(A=V^Tfrag, B=P^Tfrag) -> O^T, same lane-q. kv halves merged at the end.
__global__ __launch_bounds__(256, 3) void bsattn_main(
    const float* __restrict__ qp, const int* __restrict__ layout,
    const char* __restrict__ kimg, const char* __restrict__ vimg,
    float* __restrict__ out) {
  __shared__ alignas(16) char smem[49152];
  char* Klds = smem;          // 16KB: [128 kv][128B] swizzled
  char* Vlds = smem + 16384;  // 16KB: [64 d][256B] swizzled (V^T)
  char* Pall = smem + 32768;  // 16KB: wave*4KB, qc*2KB: [16 q][128B] swizzled

  const int tid = threadIdx.x, lane = tid & 63, wid = tid >> 6;
  const int wq = wid >> 1, wk = wid & 1;
  const int l16 = lane & 15, lg = lane >> 4;

  const int bidx = blockIdx.x;
  const int b = bidx & 7;          // one batch per XCD (round-robin dispatch)
  const int idx = bidx >> 3;       // 0..63
  const int half = idx & 1, qb = idx >> 1;
  const int q0 = qb * 128 + half * 64 + wq * 32;

  // Q fragments (B-operand: lane holds col q=l16, k=d slice), pre-scaled log2e/sqrt(D)
  const float qscale = 0.18033688011112042f;
  s16x8 qf[2][2];
  {
    const float* qbase = qp + ((size_t)b * SS + q0) * DD;
#pragma unroll
    for (int qc = 0; qc < 2; ++qc) {
      const float* qrow = qbase + (qc * 16 + l16) * DD;
#pragma unroll
      for (int kc = 0; kc < 2; ++kc) {
        const float* p0 = qrow + kc * 32 + lg * 8;
        float4 x = *(const float4*)(p0);
        float4 y = *(const float4*)(p0 + 4);
        s16x8 f;
        f[0] = (short)f2bf(x.x * qscale); f[1] = (short)f2bf(x.y * qscale);
        f[2] = (short)f2bf(x.z * qscale); f[3] = (short)f2bf(x.w * qscale);
        f[4] = (short)f2bf(y.x * qscale); f[5] = (short)f2bf(y.y * qscale);
        f[6] = (short)f2bf(y.z * qscale); f[7] = (short)f2bf(y.w * qscale);
        qf[qc][kc] = f;
      }
    }
  }

  f32x4 o_acc[2][4];
  float mreg[2], lreg[2];
#pragma unroll
  for (int qc = 0; qc < 2; ++qc) {
    mreg[qc] = -INFINITY;
    lreg[qc] = 0.0f;
#pragma unroll
    for (int dch = 0; dch < 4; ++dch) o_acc[qc][dch] = (f32x4)(0.0f);
  }

  char* Pw = Pall + wid * 4096;
  const int swp = (l16 & 7) << 4;

  for (int kb = 0; kb < NBB; ++kb) {
    if (layout[qb * NBB + kb] == 0) continue;
    __syncthreads();  // prior block's LDS reads done before overwrite
    {
      const size_t blkoff = ((size_t)(b * NBB + kb) << 14) + wid * 4096 + lane * 16;
      const char* ks = kimg + blkoff;
      const char* vs = vimg + blkoff;
#pragma unroll
      for (int i = 0; i < 4; ++i) {
        gl_lds16(ks + i * 1024, Klds + wid * 4096 + i * 1024);
        gl_lds16(vs + i * 1024, Vlds + wid * 4096 + i * 1024);
      }
    }
    asm volatile("s_waitcnt vmcnt(0)" ::: "memory");
    __syncthreads();

    // ---- QK^T (S^T: rows kv, cols q) ----
    f32x4 sc[2][4];
#pragma unroll
    for (int qc = 0; qc < 2; ++qc)
#pragma unroll
      for (int kvc = 0; kvc < 4; ++kvc) sc[qc][kvc] = (f32x4)(0.0f);
#pragma unroll
    for (int kvc = 0; kvc < 4; ++kvc) {
      int kv = wk * 64 + kvc * 16 + l16;
      const char* kr = Klds + kv * 128;
      int sw = (kv & 7) << 4;
#pragma unroll
      for (int kc = 0; kc < 2; ++kc) {
        s16x8 ak = *(const s16x8*)(kr + ((kc * 64 + lg * 16) ^ sw));
        sc[0][kvc] = MFMA16(ak, qf[0][kc], sc[0][kvc]);
        sc[1][kvc] = MFMA16(ak, qf[1][kc], sc[1][kvc]);
      }
    }

    // ---- online softmax: lane owns q=l16, 16 local kv + lg-reduce (2 shfl) ----
#pragma unroll
    for (int qc = 0; qc < 2; ++qc) {
      float mx = sc[qc][0][0];
#pragma unroll
      for (int kvc = 0; kvc < 4; ++kvc)
#pragma unroll
        for (int r = 0; r < 4; ++r) mx = fmaxf(mx, sc[qc][kvc][r]);
      mx = fmaxf(mx, __shfl_xor(mx, 16));
      mx = fmaxf(mx, __shfl_xor(mx, 32));
      float mn = fmaxf(mreg[qc], mx);
      float al = EXP2(mreg[qc] - mn);
      mreg[qc] = mn;
      float sm = 0.0f;
#pragma unroll
      for (int kvc = 0; kvc < 4; ++kvc) {
#pragma unroll
        for (int r = 0; r < 4; ++r) {
          float e = EXP2(sc[qc][kvc][r] - mn);
          sc[qc][kvc][r] = e;
          sm += e;
        }
      }
      sm += __shfl_xor(sm, 16);
      sm += __shfl_xor(sm, 32);
      lreg[qc] = lreg[qc] * al + sm;
#pragma unroll
      for (int dch = 0; dch < 4; ++dch) o_acc[qc][dch] *= al;
      // P -> LDS packed (8B per lane per kvc), wave-private
      char* pq = Pw + qc * 2048 + l16 * 128;
#pragma unroll
      for (int kvc = 0; kvc < 4; ++kvc) {
        ushort4 pb;
        pb.x = f2bf(sc[qc][kvc][0]);
        pb.y = f2bf(sc[qc][kvc][1]);
        pb.z = f2bf(sc[qc][kvc][2]);
        pb.w = f2bf(sc[qc][kvc][3]);
        *(ushort4*)(pq + ((kvc * 32 + lg * 8) ^ swp)) = pb;
      }
    }

    // ---- PV (O^T: rows d, cols q) ----
#pragma unroll
    for (int kc2 = 0; kc2 < 2; ++kc2) {
      s16x8 pbf[2];
#pragma unroll
      for (int qc = 0; qc < 2; ++qc)
        pbf[qc] = *(const s16x8*)(Pw + qc * 2048 + l16 * 128 +
                                  ((kc2 * 64 + lg * 16) ^ swp));
#pragma unroll
      for (int dch = 0; dch < 4; ++dch) {
        int d = dch * 16 + l16;
        s16x8 av = *(const s16x8*)(Vlds + d * 256 +
                                   ((wk * 128 + kc2 * 64 + lg * 16) ^ ((d & 7) << 4)));
        o_acc[0][dch] = MFMA16(av, pbf[0], o_acc[0][dch]);
        o_acc[1][dch] = MFMA16(av, pbf[1], o_acc[1][dch]);
      }
    }
  }

  // ---- merge kv halves: wk=1 publishes, wk=0 merges + stores ----
  __syncthreads();
  float* Opub = (float*)smem;            // [64 q][64 d] fp32 (aliases K+V: 16KB)
  float* Ml = (float*)(smem + 16384);    // m[64], l[64]
  if (wk == 1) {
#pragma unroll
    for (int qc = 0; qc < 2; ++qc) {
      int qlW = wq * 32 + qc * 16 + l16;
#pragma unroll
      for (int dch = 0; dch < 4; ++dch)
        *(f32x4*)(&Opub[qlW * 64 + dch * 16 + lg * 4]) = o_acc[qc][dch];
      if (lg == 0) {
        Ml[qlW] = mreg[qc];
        Ml[64 + qlW] = lreg[qc];
      }
    }
  }
  __syncthreads();
  if (wk == 0) {
#pragma unroll
    for (int qc = 0; qc < 2; ++qc) {
      int qlW = wq * 32 + qc * 16 + l16;
      float m1 = Ml[qlW], l1 = Ml[64 + qlW];
      float mm = fmaxf(mreg[qc], m1);
      float a0 = EXP2(mreg[qc] - mm);
      float a1 = EXP2(m1 - mm);
      float inv = 1.0f / (lreg[qc] * a0 + l1 * a1);
      float* gout = out + ((size_t)b * SS + q0 + qc * 16 + l16) * DD;
#pragma unroll
      for (int dch = 0; dch < 4; ++dch) {
        f32x4 o1 = *(const f32x4*)(&Opub[qlW * 64 + dch * 16 + lg * 4]);
        f32x4 r = (o_acc[qc][dch] * a0 + o1 * a1) * inv;
        *(f32x4*)(gout + dch * 16 + lg * 4) = r;
      }
    }
  }
}

extern "C" void kernel_launch(void* const* d_in, const int* in_sizes, int n_in,
                              void* d_out, int out_size, void* d_ws, size_t ws_size,
                              hipStream_t stream) {
  (void)in_sizes; (void)n_in; (void)out_size; (void)ws_size;
  const float* q = (const float*)d_in[0];
  const float* k = (const float*)d_in[1];
  const float* v = (const float*)d_in[2];
  const int* layout = (const int*)d_in[3];
  float* out = (float*)d_out;
  char* kimg = (char*)d_ws;                    // 4 MB
  char* vimg = (char*)d_ws + (4u << 20);       // 4 MB
  bsattn_prep<<<dim3(BB * NBB), dim3(256), 0, stream>>>(k, v, kimg, vimg);
  bsattn_main<<<dim3(512), dim3(256), 0, stream>>>(q, layout, kimg, vimg, out);
}

// Round 4
// 126.152 us; speedup vs baseline: 1.3290x; 1.0117x over previous
//
#include <hip/hip_runtime.h>

#define BB   8
#define SS   4096
#define DD   64
#define NBB  32

typedef float f32x4 __attribute__((ext_vector_type(4)));
typedef short s16x8 __attribute__((ext_vector_type(8)));

#if defined(__has_builtin)
#if __has_builtin(__builtin_amdgcn_exp2f)
#define EXP2(x) __builtin_amdgcn_exp2f(x)
#else
#define EXP2(x) exp2f(x)
#endif
#else
#define EXP2(x) exp2f(x)
#endif

#define MFMA16(a, b, c) __builtin_amdgcn_mfma_f32_16x16x32_bf16((a), (b), (c), 0, 0, 0)

__device__ __forceinline__ unsigned short f2bf(float x) {
  unsigned u = __builtin_bit_cast(unsigned, x);
  u += 0x7fffu + ((u >> 16) & 1u);
  return (unsigned short)(u >> 16);
}

__device__ __forceinline__ void gl_lds16(const void* g, void* l) {
  __builtin_amdgcn_global_load_lds(
      (const __attribute__((address_space(1))) unsigned int*)g,
      (__attribute__((address_space(3))) unsigned int*)l, 16, 0, 0);
}

// ---------------- prep ----------------
// K image (16KB/blk): byte[row*128 + ((2d) ^ ((row&7)<<4))] = bf16(K[row][d])
// V image (16KB/blk): kv = s*32+h*16+g*4+t  ->  byte[d*256 + ((s*64+g*16+h*8+2t) ^ ((d&7)<<4))]
//   (h-permuted columns so the QK^T accumulator IS the PV B-fragment, no P LDS round-trip)
__global__ __launch_bounds__(256) void bsattn_prep(
    const float* __restrict__ kp, const float* __restrict__ vp,
    char* __restrict__ kimg, char* __restrict__ vimg) {
  __shared__ float vt[128 * 68];  // fp32 V tile (row kv, col d), float4-aligned pad
  const int tid = threadIdx.x;
  const int blk = blockIdx.x;  // b*NBB + kb
  const float* kbp = kp + (size_t)blk * 128 * DD;
  const float* vbp = vp + (size_t)blk * 128 * DD;
  char* kdst = kimg + ((size_t)blk << 14);
  char* vdst = vimg + ((size_t)blk << 14);
  const int drow = tid & 15, rr = tid >> 4;
#pragma unroll
  for (int p = 0; p < 8; ++p) {
    int row = p * 16 + rr;
    float4 kx = *(const float4*)(kbp + row * DD + drow * 4);
    ushort4 k4;
    k4.x = f2bf(kx.x); k4.y = f2bf(kx.y); k4.z = f2bf(kx.z); k4.w = f2bf(kx.w);
    *(ushort4*)(kdst + row * 128 + ((drow * 8) ^ ((row & 7) << 4))) = k4;
    float4 vx = *(const float4*)(vbp + row * DD + drow * 4);
    *(float4*)(&vt[row * 68 + drow * 4]) = vx;
  }
  __syncthreads();
  const int l5 = tid & 31, dhi = tid >> 5;
  const int kv0 = l5 * 4;  // s=l5>>3, h=(l5>>2)&1, g=l5&3, t=0..3
  const int c0b = ((l5 >> 3) * 64) + ((l5 & 3) * 16) + (((l5 >> 2) & 1) * 8);
#pragma unroll
  for (int p = 0; p < 8; ++p) {
    int d = p * 8 + dhi;
    ushort4 v4;
    v4.x = f2bf(vt[(kv0 + 0) * 68 + d]);
    v4.y = f2bf(vt[(kv0 + 1) * 68 + d]);
    v4.z = f2bf(vt[(kv0 + 2) * 68 + d]);
    v4.w = f2bf(vt[(kv0 + 3) * 68 + d]);
    *(ushort4*)(vdst + d * 256 + (c0b ^ ((d & 7) << 4))) = v4;
  }
}

// ---------------- main ----------------
// WG = (b, qb, q-half): 64 q rows, 4 waves = (wq:2 x wk:2). Swapped MFMA throughout:
// QK^T -> S^T (lane owns q=l16), softmax in-register, PV B-frag = packed S^T regs
// (identity redistribution via the V image k-permutation). Double-buffered K/V staging.
__global__ __launch_bounds__(256) void bsattn_main(
    const float* __restrict__ qp, const int* __restrict__ layout,
    const char* __restrict__ kimg, const char* __restrict__ vimg,
    float* __restrict__ out) {
  __shared__ alignas(16) char smem[65536];  // buf b: K at b*32768, V^T at b*32768+16384

  const int tid = threadIdx.x, lane = tid & 63, wid = tid >> 6;
  const int wq = wid >> 1, wk = wid & 1;
  const int l16 = lane & 15, lg = lane >> 4;
  const int l7 = l16 & 7;

  const int bidx = blockIdx.x;
  const int b = bidx & 7;       // one batch per XCD
  const int idx = bidx >> 3;
  const int half = idx & 1, qb = idx >> 1;
  const int q0 = qb * 128 + half * 64 + wq * 32;

  // live-block bitmask (wave-uniform scalar)
  unsigned long long mask =
      __ballot((lane < 32) && (layout[qb * NBB + lane] != 0));
  const int nlive = __popcll(mask);
  unsigned long long rem = mask;

  // Q fragments (B-operand: col q=l16, k=d), pre-scaled by log2(e)/sqrt(D)
  const float qscale = 0.18033688011112042f;
  s16x8 qf[2][2];
  {
    const float* qbase = qp + ((size_t)b * SS + q0) * DD;
#pragma unroll
    for (int qc = 0; qc < 2; ++qc) {
      const float* qrow = qbase + (qc * 16 + l16) * DD;
#pragma unroll
      for (int kc = 0; kc < 2; ++kc) {
        const float* p0 = qrow + kc * 32 + lg * 8;
        float4 x = *(const float4*)(p0);
        float4 y = *(const float4*)(p0 + 4);
        s16x8 f;
        f[0] = (short)f2bf(x.x * qscale); f[1] = (short)f2bf(x.y * qscale);
        f[2] = (short)f2bf(x.z * qscale); f[3] = (short)f2bf(x.w * qscale);
        f[4] = (short)f2bf(y.x * qscale); f[5] = (short)f2bf(y.y * qscale);
        f[6] = (short)f2bf(y.z * qscale); f[7] = (short)f2bf(y.w * qscale);
        qf[qc][kc] = f;
      }
    }
  }

  f32x4 o_acc[2][4];
  float mreg[2], lreg[2];
#pragma unroll
  for (int qc = 0; qc < 2; ++qc) {
    mreg[qc] = -INFINITY;
    lreg[qc] = 0.0f;
#pragma unroll
    for (int dch = 0; dch < 4; ++dch) o_acc[qc][dch] = (f32x4)(0.0f);
  }

  const size_t imgbase = ((size_t)(b * NBB) << 14);
  const int st_g = wid * 4096 + lane * 16;  // global src offset (per-lane)
  const int st_l = wid * 4096;              // LDS dst offset (wave-uniform)

#define STAGE(bufsel, kbv)                                              \
  do {                                                                  \
    const char* ks_ = kimg + imgbase + ((size_t)(kbv) << 14) + st_g;    \
    const char* vs_ = vimg + imgbase + ((size_t)(kbv) << 14) + st_g;    \
    char* kd_ = smem + (bufsel) * 32768 + st_l;                         \
    char* vd_ = smem + (bufsel) * 32768 + 16384 + st_l;                 \
    _Pragma("unroll")                                                   \
    for (int i_ = 0; i_ < 4; ++i_) {                                    \
      gl_lds16(ks_ + i_ * 1024, kd_ + i_ * 1024);                       \
      gl_lds16(vs_ + i_ * 1024, vd_ + i_ * 1024);                       \
    }                                                                   \
  } while (0)

  // prologue: stage first live block
  {
    int kb0 = (int)__builtin_ctzll(rem);
    rem &= rem - 1;
    STAGE(0, kb0);
  }
  asm volatile("s_waitcnt vmcnt(0)" ::: "memory");
  __syncthreads();

  int buf = 0;
  for (int i = 0; i < nlive; ++i) {
    if (i + 1 < nlive) {  // wave-uniform
      int kbn = (int)__builtin_ctzll(rem);
      rem &= rem - 1;
      STAGE(buf ^ 1, kbn);
    }
    const char* Kb = smem + buf * 32768;
    const char* Vb = Kb + 16384;

    // ---- QK^T (S^T: rows kv, cols q) ----
    f32x4 sc[2][4];
#pragma unroll
    for (int qc = 0; qc < 2; ++qc)
#pragma unroll
      for (int kvc = 0; kvc < 4; ++kvc) sc[qc][kvc] = (f32x4)(0.0f);
    __builtin_amdgcn_s_setprio(1);
#pragma unroll
    for (int kvc = 0; kvc < 4; ++kvc) {
      const char* kr = Kb + (wk * 64 + kvc * 16 + l16) * 128;
#pragma unroll
      for (int kc = 0; kc < 2; ++kc) {
        s16x8 ak = *(const s16x8*)(kr + (((kc * 4 + lg) ^ l7) << 4));
        sc[0][kvc] = MFMA16(ak, qf[0][kc], sc[0][kvc]);
        sc[1][kvc] = MFMA16(ak, qf[1][kc], sc[1][kvc]);
      }
    }
    __builtin_amdgcn_s_setprio(0);

    // ---- online softmax (in-register; log2 units) + pack P fragments ----
    s16x8 pf[2][2];
#pragma unroll
    for (int qc = 0; qc < 2; ++qc) {
      f32x4* s4 = sc[qc];
      float mx = fmaxf(fmaxf(fmaxf(s4[0][0], s4[0][1]), fmaxf(s4[0][2], s4[0][3])),
                       fmaxf(fmaxf(s4[1][0], s4[1][1]), fmaxf(s4[1][2], s4[1][3])));
      mx = fmaxf(mx, fmaxf(fmaxf(fmaxf(s4[2][0], s4[2][1]), fmaxf(s4[2][2], s4[2][3])),
                           fmaxf(fmaxf(s4[3][0], s4[3][1]), fmaxf(s4[3][2], s4[3][3]))));
      mx = fmaxf(mx, __shfl_xor(mx, 16));
      mx = fmaxf(mx, __shfl_xor(mx, 32));
      // defer-max (T13): only rescale when the running max grew by > 5 (log2)
      if (!__all(mx - mreg[qc] <= 5.0f)) {
        float mn = fmaxf(mreg[qc], mx);
        float al = EXP2(mreg[qc] - mn);
        mreg[qc] = mn;
        lreg[qc] *= al;
#pragma unroll
        for (int dch = 0; dch < 4; ++dch) o_acc[qc][dch] *= al;
      }
      const float mn = mreg[qc];
      float sm = 0.0f;
#pragma unroll
      for (int kvc = 0; kvc < 4; ++kvc)
#pragma unroll
        for (int r = 0; r < 4; ++r) {
          float e = EXP2(s4[kvc][r] - mn);
          s4[kvc][r] = e;
          sm += e;
        }
      sm += __shfl_xor(sm, 16);
      sm += __shfl_xor(sm, 32);
      lreg[qc] += sm;
      // pack P^T fragments: j=h*4+t <-> acc tile (kc2*2+h), elem t — identity lanes
#pragma unroll
      for (int kc2 = 0; kc2 < 2; ++kc2) {
        s16x8 u;
        u[0] = (short)f2bf(s4[kc2 * 2][0]);     u[1] = (short)f2bf(s4[kc2 * 2][1]);
        u[2] = (short)f2bf(s4[kc2 * 2][2]);     u[3] = (short)f2bf(s4[kc2 * 2][3]);
        u[4] = (short)f2bf(s4[kc2 * 2 + 1][0]); u[5] = (short)f2bf(s4[kc2 * 2 + 1][1]);
        u[6] = (short)f2bf(s4[kc2 * 2 + 1][2]); u[7] = (short)f2bf(s4[kc2 * 2 + 1][3]);
        pf[qc][kc2] = u;
      }
    }

    // ---- PV (O^T += V^T * P^T), k-mapping matches the permuted V image ----
    __builtin_amdgcn_s_setprio(1);
#pragma unroll
    for (int kc2 = 0; kc2 < 2; ++kc2) {
      const int colb = (((wk * 8 + kc2 * 4 + lg) ^ l7) << 4);
#pragma unroll
      for (int dch = 0; dch < 4; ++dch) {
        s16x8 av = *(const s16x8*)(Vb + (dch * 16 + l16) * 256 + colb);
        o_acc[0][dch] = MFMA16(av, pf[0][kc2], o_acc[0][dch]);
        o_acc[1][dch] = MFMA16(av, pf[1][kc2], o_acc[1][dch]);
      }
    }
    __builtin_amdgcn_s_setprio(0);

    asm volatile("s_waitcnt vmcnt(0)" ::: "memory");  // next-block stage landed
    __syncthreads();
    buf ^= 1;
  }

  // ---- merge kv halves: wk=1 publishes, wk=0 merges + stores ----
  float* Opub = (float*)smem;          // [64 q][64 d] fp32 (16KB, aliases buf0 K)
  float* Ml = (float*)(smem + 16384);  // m[64], l[64] (aliases buf0 V)
  if (wk == 1) {
#pragma unroll
    for (int qc = 0; qc < 2; ++qc) {
      int qlW = wq * 32 + qc * 16 + l16;
#pragma unroll
      for (int dch = 0; dch < 4; ++dch)
        *(f32x4*)(&Opub[qlW * 64 + dch * 16 + lg * 4]) = o_acc[qc][dch];
      if (lg == 0) {
        Ml[qlW] = mreg[qc];
        Ml[64 + qlW] = lreg[qc];
      }
    }
  }
  __syncthreads();
  if (wk == 0) {
#pragma unroll
    for (int qc = 0; qc < 2; ++qc) {
      int qlW = wq * 32 + qc * 16 + l16;
      float m1 = Ml[qlW], l1 = Ml[64 + qlW];
      float mm = fmaxf(mreg[qc], m1);
      float a0 = EXP2(mreg[qc] - mm);
      float a1 = EXP2(m1 - mm);
      float inv = 1.0f / (lreg[qc] * a0 + l1 * a1);
      float* gout = out + ((size_t)b * SS + q0 + qc * 16 + l16) * DD;
#pragma unroll
      for (int dch = 0; dch < 4; ++dch) {
        f32x4 o1 = *(const f32x4*)(&Opub[qlW * 64 + dch * 16 + lg * 4]);
        f32x4 r = (o_acc[qc][dch] * a0 + o1 * a1) * inv;
        *(f32x4*)(gout + dch * 16 + lg * 4) = r;
      }
    }
  }
#undef STAGE
}

extern "C" void kernel_launch(void* const* d_in, const int* in_sizes, int n_in,
                              void* d_out, int out_size, void* d_ws, size_t ws_size,
                              hipStream_t stream) {
  (void)in_sizes; (void)n_in; (void)out_size; (void)ws_size;
  const float* q = (const float*)d_in[0];
  const float* k = (const float*)d_in[1];
  const float* v = (const float*)d_in[2];
  const int* layout = (const int*)d_in[3];
  float* out = (float*)d_out;
  char* kimg = (char*)d_ws;               // 4 MB
  char* vimg = (char*)d_ws + (4u << 20);  // 4 MB
  bsattn_prep<<<dim3(BB * NBB), dim3(256), 0, stream>>>(k, v, kimg, vimg);
  bsattn_main<<<dim3(512), dim3(256), 0, stream>>>(q, layout, kimg, vimg, out);
}

// Round 5
// 120.545 us; speedup vs baseline: 1.3908x; 1.0465x over previous
//
#include <hip/hip_runtime.h>

#define BB   8
#define SS   4096
#define DD   64
#define NBB  32

typedef float f32x4 __attribute__((ext_vector_type(4)));
typedef short s16x8 __attribute__((ext_vector_type(8)));

#if defined(__has_builtin)
#if __has_builtin(__builtin_amdgcn_exp2f)
#define EXP2(x) __builtin_amdgcn_exp2f(x)
#else
#define EXP2(x) exp2f(x)
#endif
#else
#define EXP2(x) exp2f(x)
#endif

#define MFMA16(a, b, c) __builtin_amdgcn_mfma_f32_16x16x32_bf16((a), (b), (c), 0, 0, 0)

__device__ __forceinline__ unsigned short f2bf(float x) {
  unsigned u = __builtin_bit_cast(unsigned, x);
  u += 0x7fffu + ((u >> 16) & 1u);
  return (unsigned short)(u >> 16);
}

__device__ __forceinline__ void gl_lds16(const void* g, void* l) {
  __builtin_amdgcn_global_load_lds(
      (const __attribute__((address_space(1))) unsigned int*)g,
      (__attribute__((address_space(3))) unsigned int*)l, 16, 0, 0);
}

// ---------------- prep (512 thr) ----------------
// K image (16KB/blk): byte[row*128 + ((2d) ^ ((row&7)<<4))] = bf16(K[row][d])
// V image (16KB/blk): kv = s*32+h*16+g*4+t -> byte[d*256 + ((s*64+g*16+h*8+2t) ^ ((d&7)<<4))]
//   (h-permuted columns so the QK^T accumulator IS the PV B-fragment)
__global__ __launch_bounds__(512) void bsattn_prep(
    const float* __restrict__ kp, const float* __restrict__ vp,
    char* __restrict__ kimg, char* __restrict__ vimg) {
  __shared__ float vt[128 * 68];  // fp32 V tile (row kv, col d), padded
  const int tid = threadIdx.x;
  const int blk = blockIdx.x;  // b*NBB + kb
  const float* kbp = kp + (size_t)blk * 128 * DD;
  const float* vbp = vp + (size_t)blk * 128 * DD;
  char* kdst = kimg + ((size_t)blk << 14);
  char* vdst = vimg + ((size_t)blk << 14);
  const int drow = tid & 15, rr = tid >> 4;  // rr 0..31
#pragma unroll
  for (int p = 0; p < 4; ++p) {
    int row = p * 32 + rr;
    float4 kx = *(const float4*)(kbp + row * DD + drow * 4);
    ushort4 k4;
    k4.x = f2bf(kx.x); k4.y = f2bf(kx.y); k4.z = f2bf(kx.z); k4.w = f2bf(kx.w);
    *(ushort4*)(kdst + row * 128 + ((drow * 8) ^ ((row & 7) << 4))) = k4;
    float4 vx = *(const float4*)(vbp + row * DD + drow * 4);
    *(float4*)(&vt[row * 68 + drow * 4]) = vx;
  }
  __syncthreads();
  const int l5 = tid & 31, dtop = tid >> 5;  // dtop 0..15
  const int kv0 = l5 * 4;  // s=l5>>3, h=(l5>>2)&1, g=l5&3
  const int c0b = ((l5 >> 3) * 64) + ((l5 & 3) * 16) + (((l5 >> 2) & 1) * 8);
#pragma unroll
  for (int p = 0; p < 4; ++p) {
    int d = p * 16 + dtop;
    ushort4 v4;
    v4.x = f2bf(vt[(kv0 + 0) * 68 + d]);
    v4.y = f2bf(vt[(kv0 + 1) * 68 + d]);
    v4.z = f2bf(vt[(kv0 + 2) * 68 + d]);
    v4.w = f2bf(vt[(kv0 + 3) * 68 + d]);
    *(ushort4*)(vdst + d * 256 + (c0b ^ ((d & 7) << 4))) = v4;
  }
}

// ---------------- main ----------------
// WG = (b, qb, q-half): 64 q rows, 8 waves = (wq:4 x 16 q-rows) x (wk:2 kv-halves).
// 2 WG/CU (64KB LDS) -> 16 waves/CU. Swapped MFMA; softmax in-register; PV B-frag =
// packed QK accumulator (identity lanes via the V-image k-permutation).
__global__ __launch_bounds__(512, 4) void bsattn_main(
    const float* __restrict__ qp, const int* __restrict__ layout,
    const char* __restrict__ kimg, const char* __restrict__ vimg,
    float* __restrict__ out) {
  __shared__ alignas(16) char smem[65536];  // buf b: K at b*32768, V^T at +16384

  const int tid = threadIdx.x, lane = tid & 63, wid = tid >> 6;
  const int wq = wid >> 1, wk = wid & 1;
  const int l16 = lane & 15, lg = lane >> 4;
  const int l7 = l16 & 7;

  const int bidx = blockIdx.x;
  const int b = bidx & 7;       // one batch per XCD
  const int idx = bidx >> 3;
  const int half = idx & 1, qb = idx >> 1;
  const int q0 = qb * 128 + half * 64;
  const int qrow_g = q0 + wq * 16 + l16;  // this lane's q row (global)

  // live-block bitmask (wave-uniform scalar)
  unsigned long long mask =
      __ballot((lane < 32) && (layout[qb * NBB + lane] != 0));
  const int nlive = __popcll(mask);
  unsigned long long rem = mask;

  // Q fragment (B-operand: col q=l16, k=d), pre-scaled by log2(e)/sqrt(D)
  const float qscale = 0.18033688011112042f;
  s16x8 qf[2];
  {
    const float* qrow = qp + ((size_t)b * SS + qrow_g) * DD;
#pragma unroll
    for (int kc = 0; kc < 2; ++kc) {
      const float* p0 = qrow + kc * 32 + lg * 8;
      float4 x = *(const float4*)(p0);
      float4 y = *(const float4*)(p0 + 4);
      s16x8 f;
      f[0] = (short)f2bf(x.x * qscale); f[1] = (short)f2bf(x.y * qscale);
      f[2] = (short)f2bf(x.z * qscale); f[3] = (short)f2bf(x.w * qscale);
      f[4] = (short)f2bf(y.x * qscale); f[5] = (short)f2bf(y.y * qscale);
      f[6] = (short)f2bf(y.z * qscale); f[7] = (short)f2bf(y.w * qscale);
      qf[kc] = f;
    }
  }

  f32x4 o_acc[4];
  float mreg = -INFINITY, lreg = 0.0f;
#pragma unroll
  for (int dch = 0; dch < 4; ++dch) o_acc[dch] = (f32x4)(0.0f);

  const size_t imgbase = ((size_t)(b * NBB) << 14);
  const int st_g = wid * 2048 + lane * 16;  // global src offset (per-lane)
  const int st_l = wid * 2048;              // LDS dst offset (wave-uniform)

#define STAGE(bufsel, kbv)                                              \
  do {                                                                  \
    const char* ks_ = kimg + imgbase + ((size_t)(kbv) << 14) + st_g;    \
    const char* vs_ = vimg + imgbase + ((size_t)(kbv) << 14) + st_g;    \
    char* kd_ = smem + (bufsel) * 32768 + st_l;                         \
    char* vd_ = smem + (bufsel) * 32768 + 16384 + st_l;                 \
    _Pragma("unroll")                                                   \
    for (int i_ = 0; i_ < 2; ++i_) {                                    \
      gl_lds16(ks_ + i_ * 1024, kd_ + i_ * 1024);                       \
      gl_lds16(vs_ + i_ * 1024, vd_ + i_ * 1024);                       \
    }                                                                   \
  } while (0)

  // prologue: stage first live block
  {
    int kb0 = (int)__builtin_ctzll(rem);
    rem &= rem - 1;
    STAGE(0, kb0);
  }
  asm volatile("s_waitcnt vmcnt(0)" ::: "memory");
  __syncthreads();

  int buf = 0;
  for (int i = 0; i < nlive; ++i) {
    if (i + 1 < nlive) {  // wave-uniform
      int kbn = (int)__builtin_ctzll(rem);
      rem &= rem - 1;
      STAGE(buf ^ 1, kbn);
    }
    const char* Kb = smem + buf * 32768;
    const char* Vb = Kb + 16384;

    // ---- QK^T (S^T: rows kv, cols q=l16) ----
    f32x4 sc[4];
#pragma unroll
    for (int kvc = 0; kvc < 4; ++kvc) sc[kvc] = (f32x4)(0.0f);
    __builtin_amdgcn_s_setprio(1);
#pragma unroll
    for (int kvc = 0; kvc < 4; ++kvc) {
      const char* kr = Kb + (wk * 64 + kvc * 16 + l16) * 128;
#pragma unroll
      for (int kc = 0; kc < 2; ++kc) {
        s16x8 ak = *(const s16x8*)(kr + (((kc * 4 + lg) ^ l7) << 4));
        sc[kvc] = MFMA16(ak, qf[kc], sc[kvc]);
      }
    }
    __builtin_amdgcn_s_setprio(0);

    // ---- online softmax (in-register; log2 units) + pack P fragments ----
    float mx = fmaxf(fmaxf(fmaxf(sc[0][0], sc[0][1]), fmaxf(sc[0][2], sc[0][3])),
                     fmaxf(fmaxf(sc[1][0], sc[1][1]), fmaxf(sc[1][2], sc[1][3])));
    mx = fmaxf(mx, fmaxf(fmaxf(fmaxf(sc[2][0], sc[2][1]), fmaxf(sc[2][2], sc[2][3])),
                         fmaxf(fmaxf(sc[3][0], sc[3][1]), fmaxf(sc[3][2], sc[3][3]))));
    mx = fmaxf(mx, __shfl_xor(mx, 16));
    mx = fmaxf(mx, __shfl_xor(mx, 32));
    // defer-max (T13): only rescale when the running max grew by > 5 (log2)
    if (!__all(mx - mreg <= 5.0f)) {
      float mn = fmaxf(mreg, mx);
      float al = EXP2(mreg - mn);
      mreg = mn;
      lreg *= al;
#pragma unroll
      for (int dch = 0; dch < 4; ++dch) o_acc[dch] *= al;
    }
    {
      const float mn = mreg;
      float sm = 0.0f;
#pragma unroll
      for (int kvc = 0; kvc < 4; ++kvc)
#pragma unroll
        for (int r = 0; r < 4; ++r) {
          float e = EXP2(sc[kvc][r] - mn);
          sc[kvc][r] = e;
          sm += e;
        }
      sm += __shfl_xor(sm, 16);
      sm += __shfl_xor(sm, 32);
      lreg += sm;
    }
    s16x8 pf[2];
#pragma unroll
    for (int kc2 = 0; kc2 < 2; ++kc2) {
      s16x8 u;
      u[0] = (short)f2bf(sc[kc2 * 2][0]);     u[1] = (short)f2bf(sc[kc2 * 2][1]);
      u[2] = (short)f2bf(sc[kc2 * 2][2]);     u[3] = (short)f2bf(sc[kc2 * 2][3]);
      u[4] = (short)f2bf(sc[kc2 * 2 + 1][0]); u[5] = (short)f2bf(sc[kc2 * 2 + 1][1]);
      u[6] = (short)f2bf(sc[kc2 * 2 + 1][2]); u[7] = (short)f2bf(sc[kc2 * 2 + 1][3]);
      pf[kc2] = u;
    }

    // ---- PV (O^T += V^T * P^T), k-mapping matches the permuted V image ----
    __builtin_amdgcn_s_setprio(1);
#pragma unroll
    for (int kc2 = 0; kc2 < 2; ++kc2) {
      const int colb = (((wk * 8 + kc2 * 4 + lg) ^ l7) << 4);
#pragma unroll
      for (int dch = 0; dch < 4; ++dch) {
        s16x8 av = *(const s16x8*)(Vb + (dch * 16 + l16) * 256 + colb);
        o_acc[dch] = MFMA16(av, pf[kc2], o_acc[dch]);
      }
    }
    __builtin_amdgcn_s_setprio(0);

    asm volatile("s_waitcnt vmcnt(0)" ::: "memory");  // next-block stage landed
    __syncthreads();
    buf ^= 1;
  }

  // ---- merge kv halves: wk=1 publishes, wk=0 merges + stores ----
  float* Opub = (float*)smem;          // [64 q][64 d] fp32 (16KB, aliases buf0 K)
  float* Ml = (float*)(smem + 16384);  // m[64], l[64] (aliases buf0 V)
  const int qlW = wq * 16 + l16;       // 0..63
  if (wk == 1) {
#pragma unroll
    for (int dch = 0; dch < 4; ++dch)
      *(f32x4*)(&Opub[qlW * 64 + dch * 16 + lg * 4]) = o_acc[dch];
    if (lg == 0) {
      Ml[qlW] = mreg;
      Ml[64 + qlW] = lreg;
    }
  }
  __syncthreads();
  if (wk == 0) {
    float m1 = Ml[qlW], l1 = Ml[64 + qlW];
    float mm = fmaxf(mreg, m1);
    float a0 = EXP2(mreg - mm);
    float a1 = EXP2(m1 - mm);
    float inv = 1.0f / (lreg * a0 + l1 * a1);
    float* gout = out + ((size_t)b * SS + qrow_g) * DD;
#pragma unroll
    for (int dch = 0; dch < 4; ++dch) {
      f32x4 o1 = *(const f32x4*)(&Opub[qlW * 64 + dch * 16 + lg * 4]);
      f32x4 r = (o_acc[dch] * a0 + o1 * a1) * inv;
      *(f32x4*)(gout + dch * 16 + lg * 4) = r;
    }
  }
#undef STAGE
}

extern "C" void kernel_launch(void* const* d_in, const int* in_sizes, int n_in,
                              void* d_out, int out_size, void* d_ws, size_t ws_size,
                              hipStream_t stream) {
  (void)in_sizes; (void)n_in; (void)out_size; (void)ws_size;
  const float* q = (const float*)d_in[0];
  const float* k = (const float*)d_in[1];
  const float* v = (const float*)d_in[2];
  const int* layout = (const int*)d_in[3];
  float* out = (float*)d_out;
  char* kimg = (char*)d_ws;               // 4 MB
  char* vimg = (char*)d_ws + (4u << 20);  // 4 MB
  bsattn_prep<<<dim3(BB * NBB), dim3(512), 0, stream>>>(k, v, kimg, vimg);
  bsattn_main<<<dim3(512), dim3(512), 0, stream>>>(q, layout, kimg, vimg, out);
}